// Round 1
// baseline (104.333 us; speedup 1.0000x reference)
//
#include <hip/hip_runtime.h>

#define AM_THREADS 256

// Kernel 1: per-row argmax over vocab. One block per output row.
// JAX argmax tie-break: first (lowest) index among maxima.
__global__ __launch_bounds__(AM_THREADS) void argmax_rows_kernel(
    const float* __restrict__ logits,
    const int* __restrict__ tli,
    int* __restrict__ posterior,
    int vocab)
{
    const int row = blockIdx.x;
    const long long src_row = (long long)tli[row] * (long long)vocab;
    const float* rowp = logits + src_row;

    float bestv = -INFINITY;
    int besti = 0;

    const int nvec = vocab >> 2;  // float4 chunks
    const float4* p4 = reinterpret_cast<const float4*>(rowp);

    // Ascending index order per thread + strictly-greater update => earliest
    // max kept within a thread. Cross-thread ties resolved in reduction.
    #pragma unroll 4
    for (int i = threadIdx.x; i < nvec; i += AM_THREADS) {
        float4 v = p4[i];
        const int base = i << 2;
        if (v.x > bestv) { bestv = v.x; besti = base;     }
        if (v.y > bestv) { bestv = v.y; besti = base + 1; }
        if (v.z > bestv) { bestv = v.z; besti = base + 2; }
        if (v.w > bestv) { bestv = v.w; besti = base + 3; }
    }
    // tail (vocab not multiple of 4) — robustness, no-op for 128000
    for (int i = (nvec << 2) + threadIdx.x; i < vocab; i += AM_THREADS) {
        float v = rowp[i];
        if (v > bestv) { bestv = v; besti = i; }
    }

    // wave64 butterfly reduce with first-index tie-break
    for (int off = 32; off > 0; off >>= 1) {
        float ov = __shfl_down(bestv, off);
        int   oi = __shfl_down(besti, off);
        if (ov > bestv || (ov == bestv && oi < besti)) { bestv = ov; besti = oi; }
    }

    __shared__ float sv[AM_THREADS / 64];
    __shared__ int   si[AM_THREADS / 64];
    const int wave = threadIdx.x >> 6;
    const int lane = threadIdx.x & 63;
    if (lane == 0) { sv[wave] = bestv; si[wave] = besti; }
    __syncthreads();
    if (threadIdx.x == 0) {
        for (int w = 1; w < AM_THREADS / 64; ++w) {
            if (sv[w] > bestv || (sv[w] == bestv && si[w] < besti)) {
                bestv = sv[w]; besti = si[w];
            }
        }
        posterior[row] = besti;
    }
}

// Kernel 2: per-request tree verification (tiny). One thread per request.
__global__ __launch_bounds__(64) void traverse_kernel(
    const int* __restrict__ posterior,  // [B*N]
    const int* __restrict__ tokens,     // [B*N]
    const int* __restrict__ children,   // [N*K]
    int* __restrict__ out,
    int B, int N, int K, int depth)
{
    const int b = blockIdx.x * blockDim.x + threadIdx.x;
    if (b >= B) return;

    const int* post = posterior + b * N;
    const int* tok  = tokens    + b * N;

    int path[8];  // depth <= 8
    int cur = 0;
    bool done = false;
    for (int s = 0; s < depth; ++s) {
        int nxt = -1;
        if (!done) {
            const int t = post[cur];
            for (int j = 0; j < K; ++j) {
                const int c = children[cur * K + j];
                if (c >= 0 && tok[c] == t) { nxt = c; break; }  // first match
            }
        }
        path[s] = nxt;
        if (nxt >= 0) cur = nxt; else done = true;
    }

    int acc_len = 1;
    for (int s = 0; s < depth; ++s) if (path[s] >= 0) acc_len++;
    const int next_tok = post[cur];

    // output layout: out_tok[B*N] | acc_idx[B*(depth+1)] | acc_len[B] |
    //                next_ids[B] | bonus[B]   (all int32)
    int* out_tok   = out;
    int* acc_idx   = out_tok + B * N;
    int* acc_len_o = acc_idx + B * (depth + 1);
    int* next_ids  = acc_len_o + B;
    int* bonus     = next_ids + B;

    int* orow = out_tok + b * N;
    for (int i = 0; i < N; ++i) orow[i] = -1;
    for (int s = 0; s < depth; ++s)
        orow[s] = (path[s] >= 0) ? tok[path[s]] : -1;
    orow[acc_len - 1] = next_tok;

    int* arow = acc_idx + b * (depth + 1);
    arow[0] = 0;
    for (int s = 0; s < depth; ++s) arow[s + 1] = path[s];

    acc_len_o[b] = acc_len;
    next_ids[b]  = next_tok;
    bonus[b]     = b * N + cur;
}

extern "C" void kernel_launch(void* const* d_in, const int* in_sizes, int n_in,
                              void* d_out, int out_size, void* d_ws, size_t ws_size,
                              hipStream_t stream) {
    const float* logits   = (const float*)d_in[0];
    const int*   tli      = (const int*)d_in[1];
    const int*   ids      = (const int*)d_in[2];
    const int*   children = (const int*)d_in[3];

    const int K = 2;
    const int N = in_sizes[3] / K;        // 63
    const int total = in_sizes[1];        // B*N = 1008
    const int B = total / N;              // 16
    const int vocab = (int)((long long)in_sizes[0] / (long long)total);  // 128000

    // depth = log2(N+1) - 1
    int depth = 0;
    { int m = N + 1; while (m > 2) { m >>= 1; depth++; } }

    int* posterior = (int*)d_ws;  // total ints of scratch

    argmax_rows_kernel<<<total, AM_THREADS, 0, stream>>>(logits, tli, posterior, vocab);
    traverse_kernel<<<1, 64, 0, stream>>>(posterior, ids, children,
                                          (int*)d_out, B, N, K, depth);
}

// Round 3
// 87.562 us; speedup vs baseline: 1.1915x; 1.1915x over previous
//
#include <hip/hip_runtime.h>

#define AM_THREADS 256

typedef float v4f __attribute__((ext_vector_type(4)));

// Kernel 1: per-row argmax over vocab. One block per output row.
// JAX argmax tie-break: first (lowest) index among maxima.
__global__ __launch_bounds__(AM_THREADS) void argmax_rows_kernel(
    const float* __restrict__ logits,
    const int* __restrict__ tli,
    int* __restrict__ posterior,
    int vocab)
{
    const int row = blockIdx.x;
    const int tid = threadIdx.x;
    const long long src_row = (long long)tli[row] * (long long)vocab;
    const float* rowp = logits + src_row;
    const v4f* p4 = reinterpret_cast<const v4f*>(rowp);
    const int nvec = vocab >> 2;  // float4 chunks

    // 4 independent accumulators -> 4 loads in flight, no serial compare chain.
    float bv0 = -INFINITY, bv1 = -INFINITY, bv2 = -INFINITY, bv3 = -INFINITY;
    int bi0 = 0, bi1 = 0, bi2 = 0, bi3 = 0;

    // Each accumulator sees an ascending index subsequence; strict '>' keeps
    // the earliest max within it. Cross-accumulator ties resolved in combine.
    #define UPD(BV, BI, V, IDX4)                                       \
        do {                                                           \
            if ((V)[0] > (BV)) { (BV) = (V)[0]; (BI) = (IDX4);     }   \
            if ((V)[1] > (BV)) { (BV) = (V)[1]; (BI) = (IDX4) + 1; }   \
            if ((V)[2] > (BV)) { (BV) = (V)[2]; (BI) = (IDX4) + 2; }   \
            if ((V)[3] > (BV)) { (BV) = (V)[3]; (BI) = (IDX4) + 3; }   \
        } while (0)

    int base = 0;
    for (; base + 4 * AM_THREADS <= nvec; base += 4 * AM_THREADS) {
        const int i0 = base + tid;
        const int i1 = i0 + AM_THREADS;
        const int i2 = i1 + AM_THREADS;
        const int i3 = i2 + AM_THREADS;
        v4f v0 = __builtin_nontemporal_load(p4 + i0);
        v4f v1 = __builtin_nontemporal_load(p4 + i1);
        v4f v2 = __builtin_nontemporal_load(p4 + i2);
        v4f v3 = __builtin_nontemporal_load(p4 + i3);
        UPD(bv0, bi0, v0, i0 << 2);
        UPD(bv1, bi1, v1, i1 << 2);
        UPD(bv2, bi2, v2, i2 << 2);
        UPD(bv3, bi3, v3, i3 << 2);
    }
    for (int i = base + tid; i < nvec; i += AM_THREADS) {
        v4f v = __builtin_nontemporal_load(p4 + i);
        UPD(bv0, bi0, v, i << 2);
    }
    // scalar tail (vocab not multiple of 4) — no-op for 128000
    for (int i = (nvec << 2) + tid; i < vocab; i += AM_THREADS) {
        float v = rowp[i];
        if (v > bv0 || (v == bv0 && i < bi0)) { bv0 = v; bi0 = i; }
    }
    #undef UPD

    // combine 4 accumulators (value desc, index asc on tie)
    float bestv = bv0; int besti = bi0;
    if (bv1 > bestv || (bv1 == bestv && bi1 < besti)) { bestv = bv1; besti = bi1; }
    if (bv2 > bestv || (bv2 == bestv && bi2 < besti)) { bestv = bv2; besti = bi2; }
    if (bv3 > bestv || (bv3 == bestv && bi3 < besti)) { bestv = bv3; besti = bi3; }

    // wave64 butterfly reduce with first-index tie-break
    for (int off = 32; off > 0; off >>= 1) {
        float ov = __shfl_down(bestv, off);
        int   oi = __shfl_down(besti, off);
        if (ov > bestv || (ov == bestv && oi < besti)) { bestv = ov; besti = oi; }
    }

    __shared__ float sv[AM_THREADS / 64];
    __shared__ int   si[AM_THREADS / 64];
    const int wave = threadIdx.x >> 6;
    const int lane = threadIdx.x & 63;
    if (lane == 0) { sv[wave] = bestv; si[wave] = besti; }
    __syncthreads();
    if (threadIdx.x == 0) {
        for (int w = 1; w < AM_THREADS / 64; ++w) {
            if (sv[w] > bestv || (sv[w] == bestv && si[w] < besti)) {
                bestv = sv[w]; besti = si[w];
            }
        }
        posterior[row] = besti;
    }
}

// Kernel 2: per-request tree verification (tiny). One thread per request.
__global__ __launch_bounds__(64) void traverse_kernel(
    const int* __restrict__ posterior,  // [B*N]
    const int* __restrict__ tokens,     // [B*N]
    const int* __restrict__ children,   // [N*K]
    int* __restrict__ out,
    int B, int N, int K, int depth)
{
    const int b = blockIdx.x * blockDim.x + threadIdx.x;
    if (b >= B) return;

    const int* post = posterior + b * N;
    const int* tok  = tokens    + b * N;

    int path[8];  // depth <= 8
    int cur = 0;
    bool done = false;
    for (int s = 0; s < depth; ++s) {
        int nxt = -1;
        if (!done) {
            const int t = post[cur];
            for (int j = 0; j < K; ++j) {
                const int c = children[cur * K + j];
                if (c >= 0 && tok[c] == t) { nxt = c; break; }  // first match
            }
        }
        path[s] = nxt;
        if (nxt >= 0) cur = nxt; else done = true;
    }

    int acc_len = 1;
    for (int s = 0; s < depth; ++s) if (path[s] >= 0) acc_len++;
    const int next_tok = post[cur];

    // output layout: out_tok[B*N] | acc_idx[B*(depth+1)] | acc_len[B] |
    //                next_ids[B] | bonus[B]   (all int32)
    int* out_tok   = out;
    int* acc_idx   = out_tok + B * N;
    int* acc_len_o = acc_idx + B * (depth + 1);
    int* next_ids  = acc_len_o + B;
    int* bonus     = next_ids + B;

    int* orow = out_tok + b * N;
    for (int i = 0; i < N; ++i) orow[i] = -1;
    for (int s = 0; s < depth; ++s)
        orow[s] = (path[s] >= 0) ? tok[path[s]] : -1;
    orow[acc_len - 1] = next_tok;

    int* arow = acc_idx + b * (depth + 1);
    arow[0] = 0;
    for (int s = 0; s < depth; ++s) arow[s + 1] = path[s];

    acc_len_o[b] = acc_len;
    next_ids[b]  = next_tok;
    bonus[b]     = b * N + cur;
}

extern "C" void kernel_launch(void* const* d_in, const int* in_sizes, int n_in,
                              void* d_out, int out_size, void* d_ws, size_t ws_size,
                              hipStream_t stream) {
    const float* logits   = (const float*)d_in[0];
    const int*   tli      = (const int*)d_in[1];
    const int*   ids      = (const int*)d_in[2];
    const int*   children = (const int*)d_in[3];

    const int K = 2;
    const int N = in_sizes[3] / K;        // 63
    const int total = in_sizes[1];        // B*N = 1008
    const int B = total / N;              // 16
    const int vocab = (int)((long long)in_sizes[0] / (long long)total);  // 128000

    // depth = log2(N+1) - 1
    int depth = 0;
    { int m = N + 1; while (m > 2) { m >>= 1; depth++; } }

    int* posterior = (int*)d_ws;  // total ints of scratch

    argmax_rows_kernel<<<total, AM_THREADS, 0, stream>>>(logits, tli, posterior, vocab);
    traverse_kernel<<<1, 64, 0, stream>>>(posterior, ids, children,
                                          (int*)d_out, B, N, K, depth);
}